// Round 1
// baseline (82.139 us; speedup 1.0000x reference)
//
#include <hip/hip_runtime.h>

// Problem constants (fixed by the reference file)
#define BQ    64        // batches
#define NG    128       // nodes per batch
#define NE    65536     // input edges
#define TOPK  16
#define AUGE  (NE + BQ * TOPK)   // 66560 edges per row after augmentation
#define MASK_WORDS 512           // 128*128 bits / 32

// Structural insight: LayerNorm over the size-1 last axis of s makes
// scores == beta (a constant) for ANY h,q,W1,W2 — (s-mu)==0 exactly.
// So top_k over `masked` picks, per batch, the first TOPK row-major
// (sl,dl) pairs that are neither diagonal nor an existing same-batch edge
// (jax.lax.top_k tie-break: lowest flattened index first).
// The MLP is dead code; only the edge bitmask matters.

// Kernel 1: copy edge_index rows into output slots, zero the bitmask,
// write added_count.
__global__ void copy_zero_kernel(const int* __restrict__ src,
                                 const int* __restrict__ dst,
                                 int* __restrict__ out,
                                 unsigned* __restrict__ mask) {
    int i = blockIdx.x * blockDim.x + threadIdx.x;
    if (i < NE) {
        out[i]        = src[i];        // aug row 0, original part
        out[AUGE + i] = dst[i];        // aug row 1, original part
    }
    if (i < BQ * MASK_WORDS) mask[i] = 0u;
    if (i == 0) out[2 * AUGE] = BQ * TOPK;   // added_count = 1024
}

// Kernel 2: scatter existing same-batch edges into per-batch 128x128 bitmask.
__global__ void build_mask_kernel(const int* __restrict__ src,
                                  const int* __restrict__ dst,
                                  unsigned* __restrict__ mask) {
    int e = blockIdx.x * blockDim.x + threadIdx.x;
    if (e >= NE) return;
    int s = src[e];
    int d = dst[e];
    int g = s >> 7;                       // batch of source node (Ng = 128)
    if ((d >> 7) != g) return;            // `same` check from reference
    int bit = ((s & 127) << 7) | (d & 127);   // sl*128 + dl
    atomicOr(&mask[g * MASK_WORDS + (bit >> 5)], 1u << (bit & 31));
}

// Kernel 3: per batch, emit first TOPK free non-diagonal pairs in
// row-major order. One thread per batch; typical exit after ~20 bits.
__global__ void select_kernel(const unsigned* __restrict__ mask,
                              int* __restrict__ out) {
    int g = blockIdx.x * blockDim.x + threadIdx.x;
    if (g >= BQ) return;
    const unsigned* m = mask + g * MASK_WORDS;
    int found = 0;
    for (int w = 0; w < MASK_WORDS && found < TOPK; ++w) {
        unsigned bits = m[w];
        if (bits == 0xFFFFFFFFu) continue;   // fully occupied word
        for (int b = 0; b < 32 && found < TOPK; ++b) {
            if (bits & (1u << b)) continue;        // existing edge
            int idx = (w << 5) | b;
            int sl = idx >> 7;
            int dl = idx & 127;
            if (sl == dl) continue;                // diagonal
            out[NE + g * TOPK + found]        = g * NG + sl;   // new_src
            out[AUGE + NE + g * TOPK + found] = g * NG + dl;   // new_dst
            ++found;
        }
    }
}

extern "C" void kernel_launch(void* const* d_in, const int* in_sizes, int n_in,
                              void* d_out, int out_size, void* d_ws, size_t ws_size,
                              hipStream_t stream) {
    // Input order per setup_inputs():
    // 0:h 1:q 2:W1 3:b1 4:W2 5:b2 6:gamma 7:beta 8:edge_index 9:node_batch 10:top_k
    const int* edge_index = (const int*)d_in[8];
    const int* e_src = edge_index;        // edge_index[0], NE elements
    const int* e_dst = edge_index + NE;   // edge_index[1], NE elements

    int* out = (int*)d_out;               // int32 output, 2*AUGE + 1 elements
    unsigned* mask = (unsigned*)d_ws;     // BQ * MASK_WORDS words = 128 KiB

    const int threads = 256;

    copy_zero_kernel<<<(NE + threads - 1) / threads, threads, 0, stream>>>(
        e_src, e_dst, out, mask);
    build_mask_kernel<<<(NE + threads - 1) / threads, threads, 0, stream>>>(
        e_src, e_dst, mask);
    select_kernel<<<1, 64, 0, stream>>>(mask, out);
}